// Round 1
// baseline (226.872 us; speedup 1.0000x reference)
//
#include <hip/hip_runtime.h>
#include <math.h>

#define S_PNTS 8
#define NUM_POINTS 2
#define NB 8
#define NQ 500
#define NC 256
#define S_SCALE 0.077f

// One block per (b,q). 256 threads: thread c owns MLP column c for all 8 s-points.
__global__ __launch_bounds__(256) void decoder_kernel(
    const float* __restrict__ ref_polys,   // (B, Q, 8)
    const int*   __restrict__ ref_levels,  // (B, Q)
    const float* __restrict__ memory,      // (B, 8500, 256)
    const float* __restrict__ W1,          // (256, 256)
    const float* __restrict__ b1,          // (256,)
    const float* __restrict__ W2,          // (256, 4)
    const float* __restrict__ b2,          // (4,)
    float*       __restrict__ out)         // (B, Q, 16, 2)
{
    const int bq  = blockIdx.x;
    const int b   = bq / NQ;
    const int tid = threadIdx.x;

    __shared__ __align__(16) float emb[S_PNTS * NC];      // 8 KB
    __shared__ float hbuf[S_PNTS * (NC + 4)];             // padded: stride 260 -> no bank conflict in layer 2
    __shared__ float spts[S_PNTS][2];

    const int lvl = ref_levels[bq];
    const int sizes[4]  = {80, 40, 20, 10};
    const int starts[4] = {0, 6400, 8000, 8400};
    const int W  = sizes[lvl];     // H == W for all levels
    const int st = starts[lvl];

    // ---- sampling points: poly eval at lam = s/7, mapped to [-1,1] ----
    if (tid < S_PNTS) {
        const float* rp = ref_polys + bq * 8;
        float lam = (float)tid * (1.0f / 7.0f);
        // coeff order: lam^3, lam^2, lam, 1  (Horner)
        float x = ((rp[0] * lam + rp[1]) * lam + rp[2]) * lam + rp[3];
        float y = ((rp[4] * lam + rp[5]) * lam + rp[6]) * lam + rp[7];
        spts[tid][0] = 2.0f * (x - 0.5f);
        spts[tid][1] = 2.0f * (y - 0.5f);
    }
    __syncthreads();

    // ---- bilinear gather: emb[s][c] (zero padding, align_corners=False) ----
    const float* mem_b = memory + ((size_t)b * 8500 + st) * NC;
    #pragma unroll
    for (int s = 0; s < S_PNTS; ++s) {
        float gx = (spts[s][0] + 1.0f) * 0.5f * (float)W - 0.5f;
        float gy = (spts[s][1] + 1.0f) * 0.5f * (float)W - 0.5f;
        float x0f = floorf(gx), y0f = floorf(gy);
        int   x0 = (int)x0f,    y0 = (int)y0f;
        float wx1 = gx - x0f, wx0 = 1.0f - wx1;
        float wy1 = gy - y0f, wy0 = 1.0f - wy1;
        bool xv0 = (x0 >= 0) && (x0 < W);
        bool xv1 = (x0 + 1 >= 0) && (x0 + 1 < W);
        bool yv0 = (y0 >= 0) && (y0 < W);
        bool yv1 = (y0 + 1 >= 0) && (y0 + 1 < W);
        float v = 0.0f;
        if (yv0 && xv0) v += wy0 * wx0 * mem_b[((size_t)(y0 * W + x0)) * NC + tid];
        if (yv0 && xv1) v += wy0 * wx1 * mem_b[((size_t)(y0 * W + x0 + 1)) * NC + tid];
        if (yv1 && xv0) v += wy1 * wx0 * mem_b[((size_t)((y0 + 1) * W + x0)) * NC + tid];
        if (yv1 && xv1) v += wy1 * wx1 * mem_b[((size_t)((y0 + 1) * W + x0 + 1)) * NC + tid];
        emb[s * NC + tid] = v;
    }
    __syncthreads();

    // ---- layer 1: h[s][c] = tanh(sum_k emb[s][k] * W1[k][c] + b1[c]) ----
    float acc[S_PNTS];
    {
        float bias = b1[tid];
        #pragma unroll
        for (int s = 0; s < S_PNTS; ++s) acc[s] = bias;
    }
    for (int k = 0; k < NC; k += 4) {
        float w0 = W1[(k + 0) * NC + tid];
        float w1 = W1[(k + 1) * NC + tid];
        float w2 = W1[(k + 2) * NC + tid];
        float w3 = W1[(k + 3) * NC + tid];
        #pragma unroll
        for (int s = 0; s < S_PNTS; ++s) {
            float4 e = *(const float4*)&emb[s * NC + k];   // wave-uniform broadcast read
            acc[s] += e.x * w0 + e.y * w1 + e.z * w2 + e.w * w3;
        }
    }
    #pragma unroll
    for (int s = 0; s < S_PNTS; ++s)
        hbuf[s * (NC + 4) + tid] = tanhf(acc[s]);
    __syncthreads();

    // ---- layer 2 + epilogue: 32 outputs (8 s x 4 j) ----
    if (tid < 32) {
        int s = tid >> 2, j = tid & 3;
        float o = b2[j];
        #pragma unroll 4
        for (int k = 0; k < NC; ++k)
            o += hbuf[s * (NC + 4) + k] * W2[k * 4 + j];
        o = S_SCALE * tanhf(o);
        int np = j >> 1, coord = j & 1;
        out[((size_t)bq * (S_PNTS * NUM_POINTS) + s * NUM_POINTS + np) * 2 + coord]
            = o + spts[s][coord];
    }
}

extern "C" void kernel_launch(void* const* d_in, const int* in_sizes, int n_in,
                              void* d_out, int out_size, void* d_ws, size_t ws_size,
                              hipStream_t stream) {
    const float* ref_polys  = (const float*)d_in[0];
    const int*   ref_levels = (const int*)d_in[1];
    const float* memory     = (const float*)d_in[2];
    const float* W1         = (const float*)d_in[3];
    const float* b1         = (const float*)d_in[4];
    const float* W2         = (const float*)d_in[5];
    const float* b2         = (const float*)d_in[6];
    float* out = (float*)d_out;

    decoder_kernel<<<dim3(NB * NQ), dim3(256), 0, stream>>>(
        ref_polys, ref_levels, memory, W1, b1, W2, b2, out);
}

// Round 2
// 137.969 us; speedup vs baseline: 1.6444x; 1.6444x over previous
//
#include <hip/hip_runtime.h>
#include <math.h>

#define S_PNTS 8
#define NUM_POINTS 2
#define NB 8
#define NQ 500
#define NC 256
#define S_SCALE 0.077f
#define QPB 4                 // queries per block
#define ROWS (QPB * S_PNTS)   // 32 M-rows per block
#define APAD 264              // A-tile LDS leading dim (bf16 elems): 264*2=528 B = 16*33 -> aligned, 2-way bank alias only

typedef __bf16 bf16x8 __attribute__((ext_vector_type(8)));
typedef __bf16 bf16x2 __attribute__((ext_vector_type(2)));
typedef float  f32x4  __attribute__((ext_vector_type(4)));

// ---- prep: W1 (256x256 fp32, [k][n]) -> W1t (256x256 bf16, [n][k]) in ws ----
__global__ __launch_bounds__(256) void prep_w1(const float* __restrict__ W1,
                                               __bf16* __restrict__ W1t) {
    __shared__ float tile[16][17];
    const int n0 = blockIdx.x * 16, k0 = blockIdx.y * 16;
    const int tx = threadIdx.x & 15, ty = threadIdx.x >> 4;
    tile[ty][tx] = W1[(k0 + ty) * NC + n0 + tx];          // coalesced read
    __syncthreads();
    W1t[(n0 + ty) * NC + k0 + tx] = (__bf16)tile[tx][ty]; // coalesced-ish 2B write
}

// ---- main: gather -> bf16 MFMA layer1 -> tanh -> layer2 -> epilogue ----
__global__ __launch_bounds__(256) void decoder_kernel(
    const float* __restrict__ ref_polys,   // (B, Q, 8)
    const int*   __restrict__ ref_levels,  // (B, Q)
    const float* __restrict__ memory,      // (B, 8500, 256)
    const __bf16* __restrict__ W1t,        // (256, 256) [n][k] bf16 (ws)
    const float* __restrict__ b1,          // (256,)
    const float* __restrict__ W2,          // (256, 4)
    const float* __restrict__ b2,          // (4,)
    float*       __restrict__ out)         // (B, Q, 16, 2)
{
    const int tid = threadIdx.x;

    __shared__ __bf16 emb_lds[ROWS * APAD];        // 16.9 KB; A-tile, then reused for h
    __shared__ float  w2t[4 * 260];                // W2 transposed [j][k], pad 260
    __shared__ float  b1_lds[NC];
    __shared__ int4   p_idx[ROWS];                 // 4 corner row-indices (clamped, absolute)
    __shared__ float4 p_w[ROWS];                   // 4 bilinear weights (validity-zeroed)
    __shared__ float2 spts_lds[ROWS];

    // ---- phase 1: per-row sampling params (32 threads) ----
    if (tid < ROWS) {
        const int r = tid, s = r & 7;
        const int qg = blockIdx.x * QPB + (r >> 3);     // global query in [0, 4000)
        const int b  = qg / NQ;
        const int lvl = ref_levels[qg];
        const int sizes[4]  = {80, 40, 20, 10};
        const int starts[4] = {0, 6400, 8000, 8400};
        const int W = sizes[lvl], st = starts[lvl];
        const float* rp = ref_polys + (size_t)qg * 8;
        float lam = (float)s * (1.0f / 7.0f);
        float sx = 2.0f * ((((rp[0] * lam + rp[1]) * lam + rp[2]) * lam + rp[3]) - 0.5f);
        float sy = 2.0f * ((((rp[4] * lam + rp[5]) * lam + rp[6]) * lam + rp[7]) - 0.5f);
        spts_lds[r] = make_float2(sx, sy);
        float gx = (sx + 1.0f) * 0.5f * (float)W - 0.5f;
        float gy = (sy + 1.0f) * 0.5f * (float)W - 0.5f;
        float x0f = floorf(gx), y0f = floorf(gy);
        int   x0 = (int)x0f,    y0 = (int)y0f;
        float wx1 = gx - x0f, wx0 = 1.0f - wx1;
        float wy1 = gy - y0f, wy0 = 1.0f - wy1;
        float xv0 = (x0 >= 0 && x0 < W) ? 1.0f : 0.0f;
        float xv1 = (x0 + 1 >= 0 && x0 + 1 < W) ? 1.0f : 0.0f;
        float yv0 = (y0 >= 0 && y0 < W) ? 1.0f : 0.0f;
        float yv1 = (y0 + 1 >= 0 && y0 + 1 < W) ? 1.0f : 0.0f;
        int xc0 = min(max(x0, 0), W - 1),     xc1 = min(max(x0 + 1, 0), W - 1);
        int yc0 = min(max(y0, 0), W - 1),     yc1 = min(max(y0 + 1, 0), W - 1);
        int base = b * 8500 + st;
        p_idx[r] = make_int4(base + yc0 * W + xc0, base + yc0 * W + xc1,
                             base + yc1 * W + xc0, base + yc1 * W + xc1);
        p_w[r] = make_float4(wy0 * wx0 * yv0 * xv0, wy0 * wx1 * yv0 * xv1,
                             wy1 * wx0 * yv1 * xv0, wy1 * wx1 * yv1 * xv1);
    }
    // ---- stage W2 (transposed fp32) + b1 into LDS ----
    #pragma unroll
    for (int i = tid; i < NC * 4; i += 256) {
        int k = i >> 2, j = i & 3;
        w2t[j * 260 + k] = W2[i];
    }
    b1_lds[tid] = b1[tid];
    __syncthreads();

    // ---- phase 2: bilinear gather -> emb_lds bf16 (A-tile) ----
    {
        const int p  = tid >> 7;        // row parity
        const int c2 = tid & 127;       // float2 channel index
        const float2* m2 = (const float2*)memory;
        #pragma unroll
        for (int i = 0; i < 16; ++i) {
            int r = i * 2 + p;
            int4   id = p_idx[r];
            float4 wv = p_w[r];
            float2 v00 = m2[(size_t)id.x * 128 + c2];
            float2 v01 = m2[(size_t)id.y * 128 + c2];
            float2 v10 = m2[(size_t)id.z * 128 + c2];
            float2 v11 = m2[(size_t)id.w * 128 + c2];
            float ex = wv.x * v00.x + wv.y * v01.x + wv.z * v10.x + wv.w * v11.x;
            float ey = wv.x * v00.y + wv.y * v01.y + wv.z * v10.y + wv.w * v11.y;
            bf16x2 e2; e2[0] = (__bf16)ex; e2[1] = (__bf16)ey;
            *(bf16x2*)&emb_lds[r * APAD + c2 * 2] = e2;
        }
    }
    __syncthreads();

    // ---- phase 3: layer-1 MFMA. wave w owns cols [w*64, w*64+64) ----
    const int w    = tid >> 6;
    const int l    = tid & 63;
    const int lrow = l & 15;     // A row / C col within tile
    const int quad = l >> 4;

    f32x4 acc[2][4] = {};
    #pragma unroll
    for (int ks = 0; ks < 8; ++ks) {
        bf16x8 a0 = *(const bf16x8*)&emb_lds[(lrow)      * APAD + ks * 32 + quad * 8];
        bf16x8 a1 = *(const bf16x8*)&emb_lds[(16 + lrow) * APAD + ks * 32 + quad * 8];
        #pragma unroll
        for (int nt = 0; nt < 4; ++nt) {
            const int n = w * 64 + nt * 16 + lrow;
            bf16x8 bf = *(const bf16x8*)&W1t[n * NC + ks * 32 + quad * 8];
            acc[0][nt] = __builtin_amdgcn_mfma_f32_16x16x32_bf16(a0, bf, acc[0][nt], 0, 0, 0);
            acc[1][nt] = __builtin_amdgcn_mfma_f32_16x16x32_bf16(a1, bf, acc[1][nt], 0, 0, 0);
        }
    }
    __syncthreads();   // all waves done reading emb A-tile before overwrite with h

    // ---- phase 4: h = tanh(acc + b1) -> bf16, back into emb_lds ----
    #pragma unroll
    for (int mt = 0; mt < 2; ++mt) {
        #pragma unroll
        for (int nt = 0; nt < 4; ++nt) {
            const int n = w * 64 + nt * 16 + lrow;
            const float bias = b1_lds[n];
            #pragma unroll
            for (int rg = 0; rg < 4; ++rg) {
                const int row = mt * 16 + quad * 4 + rg;
                emb_lds[row * APAD + n] = (__bf16)tanhf(acc[mt][nt][rg] + bias);
            }
        }
    }
    __syncthreads();

    // ---- phase 5: layer 2 + epilogue. thread = (row, j, k-half) ----
    {
        const int r    = tid >> 3;
        const int j    = (tid >> 1) & 3;
        const int half = tid & 1;
        float sum = 0.0f;
        const int kbase = half * 128;
        #pragma unroll
        for (int i = 0; i < 16; ++i) {
            const int k = kbase + i * 8;
            bf16x8 hv = *(const bf16x8*)&emb_lds[r * APAD + k];
            f32x4 wa = *(const f32x4*)&w2t[j * 260 + k];
            f32x4 wb = *(const f32x4*)&w2t[j * 260 + k + 4];
            sum += (float)hv[0] * wa[0] + (float)hv[1] * wa[1]
                 + (float)hv[2] * wa[2] + (float)hv[3] * wa[3]
                 + (float)hv[4] * wb[0] + (float)hv[5] * wb[1]
                 + (float)hv[6] * wb[2] + (float)hv[7] * wb[3];
        }
        sum += __shfl_xor(sum, 1);     // combine the two k-halves
        if (half == 0) {
            float o = S_SCALE * tanhf(sum + b2[j]);
            const int s = r & 7;
            const int qg = blockIdx.x * QPB + (r >> 3);
            const int np = j >> 1, coord = j & 1;
            float sp = (coord == 0) ? spts_lds[r].x : spts_lds[r].y;
            out[(size_t)qg * 32 + s * 4 + np * 2 + coord] = o + sp;
        }
    }
}

extern "C" void kernel_launch(void* const* d_in, const int* in_sizes, int n_in,
                              void* d_out, int out_size, void* d_ws, size_t ws_size,
                              hipStream_t stream) {
    const float* ref_polys  = (const float*)d_in[0];
    const int*   ref_levels = (const int*)d_in[1];
    const float* memory     = (const float*)d_in[2];
    const float* W1         = (const float*)d_in[3];
    const float* b1         = (const float*)d_in[4];
    const float* W2         = (const float*)d_in[5];
    const float* b2         = (const float*)d_in[6];
    float* out = (float*)d_out;

    __bf16* W1t = (__bf16*)d_ws;   // 256*256*2 = 128 KB of ws

    prep_w1<<<dim3(16, 16), dim3(256), 0, stream>>>(W1, W1t);
    decoder_kernel<<<dim3(NB * NQ / QPB), dim3(256), 0, stream>>>(
        ref_polys, ref_levels, memory, W1t, b1, W2, b2, out);
}

// Round 3
// 126.469 us; speedup vs baseline: 1.7939x; 1.0909x over previous
//
#include <hip/hip_runtime.h>
#include <math.h>

#define S_PNTS 8
#define NUM_POINTS 2
#define NB 8
#define NQ 500
#define NC 256
#define S_SCALE 0.077f
#define QPB 8                 // queries per block
#define ROWS (QPB * S_PNTS)   // 64 M-rows per block
#define APAD 264              // A/h LDS leading dim in bf16: 528 B = 33*16 -> 16B-aligned rows, 2-way bank alias only (free)

typedef __bf16 bf16x8 __attribute__((ext_vector_type(8)));
typedef __bf16 bf16x4 __attribute__((ext_vector_type(4)));
typedef float  f32x4  __attribute__((ext_vector_type(4)));

__device__ __forceinline__ float fast_tanh(float x) {
    // tanh(x) = 1 - 2/(exp2(2x*log2e)+1); clamp keeps exp2 in range, tanh(+-14) == +-1 in fp32
    float xc = fminf(fmaxf(x, -14.0f), 14.0f);
    float t  = __builtin_amdgcn_exp2f(xc * 2.88539008178f);
    return 1.0f - 2.0f * __builtin_amdgcn_rcpf(t + 1.0f);
}

// ---- prep: W1 (256x256 fp32, [k][n]) -> W1t (256x256 bf16, [n][k]) in ws ----
__global__ __launch_bounds__(256) void prep_w1(const float* __restrict__ W1,
                                               __bf16* __restrict__ W1t) {
    __shared__ float tile[16][17];
    const int n0 = blockIdx.x * 16, k0 = blockIdx.y * 16;
    const int tx = threadIdx.x & 15, ty = threadIdx.x >> 4;
    tile[ty][tx] = W1[(k0 + ty) * NC + n0 + tx];          // coalesced read
    __syncthreads();
    W1t[(n0 + ty) * NC + k0 + tx] = (__bf16)tile[tx][ty];
}

// ---- main: gather -> bf16 MFMA layer1 -> tanh -> layer2 -> epilogue ----
__global__ __launch_bounds__(256) void decoder_kernel(
    const float* __restrict__ ref_polys,   // (B, Q, 8)
    const int*   __restrict__ ref_levels,  // (B, Q)
    const float* __restrict__ memory,      // (B, 8500, 256)
    const __bf16* __restrict__ W1t,        // (256, 256) [n][k] bf16 (ws)
    const float* __restrict__ b1,          // (256,)
    const float* __restrict__ W2,          // (256, 4)
    const float* __restrict__ b2,          // (4,)
    float*       __restrict__ out)         // (B, Q, 16, 2)
{
    const int tid = threadIdx.x;

    __shared__ __bf16 emb_lds[ROWS * APAD];        // 33.8 KB; A-tile, then reused for h
    __shared__ float  w2t[4 * 260];                // W2 transposed [j][k]
    __shared__ float  b1_lds[NC];
    __shared__ int4   p_idx[ROWS];
    __shared__ float4 p_w[ROWS];
    __shared__ float2 spts_lds[ROWS];

    // ---- phase 1: per-row sampling params (one full wave) ----
    if (tid < ROWS) {
        const int r = tid, s = r & 7;
        const int qg = blockIdx.x * QPB + (r >> 3);     // global query in [0, 4000)
        const int b  = qg / NQ;
        const int lvl = ref_levels[qg];
        const int W  = 80 >> lvl;                                    // 80,40,20,10
        const int st = (lvl >= 1) * 6400 + (lvl >= 2) * 1600 + (lvl >= 3) * 400;
        const float* rp = ref_polys + (size_t)qg * 8;
        float lam = (float)s * (1.0f / 7.0f);
        float sx = 2.0f * ((((rp[0] * lam + rp[1]) * lam + rp[2]) * lam + rp[3]) - 0.5f);
        float sy = 2.0f * ((((rp[4] * lam + rp[5]) * lam + rp[6]) * lam + rp[7]) - 0.5f);
        spts_lds[r] = make_float2(sx, sy);
        float gx = (sx + 1.0f) * 0.5f * (float)W - 0.5f;
        float gy = (sy + 1.0f) * 0.5f * (float)W - 0.5f;
        float x0f = floorf(gx), y0f = floorf(gy);
        int   x0 = (int)x0f,    y0 = (int)y0f;
        float wx1 = gx - x0f, wx0 = 1.0f - wx1;
        float wy1 = gy - y0f, wy0 = 1.0f - wy1;
        float xv0 = (x0 >= 0 && x0 < W) ? 1.0f : 0.0f;
        float xv1 = (x0 + 1 >= 0 && x0 + 1 < W) ? 1.0f : 0.0f;
        float yv0 = (y0 >= 0 && y0 < W) ? 1.0f : 0.0f;
        float yv1 = (y0 + 1 >= 0 && y0 + 1 < W) ? 1.0f : 0.0f;
        int xc0 = min(max(x0, 0), W - 1),     xc1 = min(max(x0 + 1, 0), W - 1);
        int yc0 = min(max(y0, 0), W - 1),     yc1 = min(max(y0 + 1, 0), W - 1);
        int base = b * 8500 + st;
        p_idx[r] = make_int4(base + yc0 * W + xc0, base + yc0 * W + xc1,
                             base + yc1 * W + xc0, base + yc1 * W + xc1);
        p_w[r] = make_float4(wy0 * wx0 * yv0 * xv0, wy0 * wx1 * yv0 * xv1,
                             wy1 * wx0 * yv1 * xv0, wy1 * wx1 * yv1 * xv1);
    }
    // ---- stage W2 (transposed fp32) + b1 into LDS ----
    #pragma unroll
    for (int i = tid; i < NC * 4; i += 256) {
        int k = i >> 2, j = i & 3;
        w2t[j * 260 + k] = W2[i];
    }
    b1_lds[tid] = b1[tid];
    __syncthreads();

    // ---- phase 2: bilinear gather -> emb_lds bf16 (A-tile), float4 loads ----
    {
        const int c4  = tid & 63;       // float4 channel index (0..63)
        const int rg0 = tid >> 6;       // 4 rows per pass
        const float4* m4 = (const float4*)memory;
        #pragma unroll
        for (int i = 0; i < 16; ++i) {
            int r = i * 4 + rg0;
            int4   id = p_idx[r];
            float4 wv = p_w[r];
            float4 v00 = m4[(size_t)id.x * 64 + c4];
            float4 v01 = m4[(size_t)id.y * 64 + c4];
            float4 v10 = m4[(size_t)id.z * 64 + c4];
            float4 v11 = m4[(size_t)id.w * 64 + c4];
            bf16x4 e;
            e[0] = (__bf16)(wv.x * v00.x + wv.y * v01.x + wv.z * v10.x + wv.w * v11.x);
            e[1] = (__bf16)(wv.x * v00.y + wv.y * v01.y + wv.z * v10.y + wv.w * v11.y);
            e[2] = (__bf16)(wv.x * v00.z + wv.y * v01.z + wv.z * v10.z + wv.w * v11.z);
            e[3] = (__bf16)(wv.x * v00.w + wv.y * v01.w + wv.z * v10.w + wv.w * v11.w);
            *(bf16x4*)&emb_lds[r * APAD + c4 * 4] = e;
        }
    }
    __syncthreads();

    // ---- phase 3: layer-1 MFMA. wave w owns cols [w*64, w*64+64), 4 M-tiles x 4 N-tiles ----
    const int w    = tid >> 6;
    const int l    = tid & 63;
    const int lrow = l & 15;
    const int quad = l >> 4;

    f32x4 acc[4][4] = {};
    #pragma unroll
    for (int ks = 0; ks < 8; ++ks) {
        bf16x8 a[4];
        #pragma unroll
        for (int mt = 0; mt < 4; ++mt)
            a[mt] = *(const bf16x8*)&emb_lds[(mt * 16 + lrow) * APAD + ks * 32 + quad * 8];
        #pragma unroll
        for (int nt = 0; nt < 4; ++nt) {
            const int n = w * 64 + nt * 16 + lrow;
            bf16x8 bf = *(const bf16x8*)&W1t[n * NC + ks * 32 + quad * 8];
            #pragma unroll
            for (int mt = 0; mt < 4; ++mt)
                acc[mt][nt] = __builtin_amdgcn_mfma_f32_16x16x32_bf16(a[mt], bf, acc[mt][nt], 0, 0, 0);
        }
    }
    __syncthreads();   // all waves done reading emb A-tile before overwrite with h

    // ---- phase 4: h = fast_tanh(acc + b1) -> bf16, back into emb_lds ----
    #pragma unroll
    for (int mt = 0; mt < 4; ++mt) {
        #pragma unroll
        for (int nt = 0; nt < 4; ++nt) {
            const int n = w * 64 + nt * 16 + lrow;
            const float bias = b1_lds[n];
            #pragma unroll
            for (int rg = 0; rg < 4; ++rg) {
                const int row = mt * 16 + quad * 4 + rg;
                emb_lds[row * APAD + n] = (__bf16)fast_tanh(acc[mt][nt][rg] + bias);
            }
        }
    }
    __syncthreads();

    // ---- phase 5: layer 2 + epilogue. thread = (row r, output j), full-K dot ----
    {
        const int r = tid >> 2;        // 0..63
        const int j = tid & 3;
        float sum = b2[j];
        #pragma unroll
        for (int i = 0; i < 32; ++i) {
            const int k = i * 8;
            bf16x8 hv = *(const bf16x8*)&emb_lds[r * APAD + k];
            f32x4 wa = *(const f32x4*)&w2t[j * 260 + k];
            f32x4 wb = *(const f32x4*)&w2t[j * 260 + k + 4];
            sum += (float)hv[0] * wa[0] + (float)hv[1] * wa[1]
                 + (float)hv[2] * wa[2] + (float)hv[3] * wa[3]
                 + (float)hv[4] * wb[0] + (float)hv[5] * wb[1]
                 + (float)hv[6] * wb[2] + (float)hv[7] * wb[3];
        }
        float o = S_SCALE * fast_tanh(sum);
        const int s  = r & 7;
        const int qg = blockIdx.x * QPB + (r >> 3);
        const int coord = j & 1;
        float sp = (coord == 0) ? spts_lds[r].x : spts_lds[r].y;
        out[(size_t)qg * 32 + s * 4 + j] = o + sp;
    }
}

extern "C" void kernel_launch(void* const* d_in, const int* in_sizes, int n_in,
                              void* d_out, int out_size, void* d_ws, size_t ws_size,
                              hipStream_t stream) {
    const float* ref_polys  = (const float*)d_in[0];
    const int*   ref_levels = (const int*)d_in[1];
    const float* memory     = (const float*)d_in[2];
    const float* W1         = (const float*)d_in[3];
    const float* b1         = (const float*)d_in[4];
    const float* W2         = (const float*)d_in[5];
    const float* b2         = (const float*)d_in[6];
    float* out = (float*)d_out;

    __bf16* W1t = (__bf16*)d_ws;   // 128 KB of ws

    prep_w1<<<dim3(16, 16), dim3(256), 0, stream>>>(W1, W1t);
    decoder_kernel<<<dim3(NB * NQ / QPB), dim3(256), 0, stream>>>(
        ref_polys, ref_levels, memory, W1t, b1, W2, b2, out);
}